// Round 5
// baseline (600.427 us; speedup 1.0000x reference)
//
#include <hip/hip_runtime.h>

// D-FINE post-processor, two-kernel decomposition.
//   K1 (filter): flat grid-stride streaming read of all logits (float4,
//       2048x256, high occupancy -> TLP-covered HBM latency). Elements with
//       logit > THR are pushed to a per-batch global candidate list in d_ws.
//       {x > THR} is a prefix of the descending order, so if K <= n <= CAP the
//       exact top-K is contained in the list.
//   K2 (select): one block per batch; candidates -> LDS, rank-based selection
//       (count-of-greater on packed (key<<32)|~idx, exact jax.lax.top_k tie
//       semantics), decode boxes, emit. Per-batch histogram FALLBACK if the
//       bound check fails (correct for any input distribution).
// Output (float32): labels [B*K] | boxes [B*K*4] | scores [B*K]

constexpr int   NT2  = 1024;    // select kernel block
constexpr int   NBINS = 4096;
constexpr int   CAPL  = 4096;   // LDS candidate capacity (select kernel)
constexpr float THR   = 2.4f;   // static pre-filter on logits

__device__ __forceinline__ unsigned f2key(float f) {
    unsigned u = __float_as_uint(f);
    return (u & 0x80000000u) ? ~u : (u | 0x80000000u);
}
__device__ __forceinline__ float key2f(unsigned k) {
    unsigned u = (k & 0x80000000u) ? (k & 0x7FFFFFFFu) : ~k;
    return __uint_as_float(u);
}
__device__ __forceinline__ unsigned long long packkv(unsigned key, unsigned idx) {
    return ((unsigned long long)key << 32) | (unsigned long long)(0xFFFFFFFFu - idx);
}

// ---------------- Kernel 1: streaming filter ----------------
__global__ __launch_bounds__(256) void dfine_filter_kernel(
    const float4* __restrict__ lg4,          // [B*N/4]
    unsigned* __restrict__ cnt,              // [B]
    unsigned long long* __restrict__ candG,  // [B*capG]
    int TOT4, int N4, int capG)
{
    const int stride = gridDim.x * blockDim.x;
    for (int i4 = blockIdx.x * blockDim.x + threadIdx.x; i4 < TOT4; i4 += stride) {
        float4 v = lg4[i4];
        if (v.x > THR || v.y > THR || v.z > THR || v.w > THR) {   // rare (~3% of vecs)
            int b = i4 / N4;                                      // div only on hit
            unsigned base = (unsigned)(4 * (i4 - b * N4));
            unsigned long long* cb = candG + (long long)b * capG;
            if (v.x > THR) { unsigned p = atomicAdd(&cnt[b], 1u);
                if (p < (unsigned)capG) cb[p] = packkv(f2key(v.x), base + 0); }
            if (v.y > THR) { unsigned p = atomicAdd(&cnt[b], 1u);
                if (p < (unsigned)capG) cb[p] = packkv(f2key(v.y), base + 1); }
            if (v.z > THR) { unsigned p = atomicAdd(&cnt[b], 1u);
                if (p < (unsigned)capG) cb[p] = packkv(f2key(v.z), base + 2); }
            if (v.w > THR) { unsigned p = atomicAdd(&cnt[b], 1u);
                if (p < (unsigned)capG) cb[p] = packkv(f2key(v.w), base + 3); }
        }
    }
}

// ---------------- Kernel 2: per-batch select + emit ----------------
__global__ __launch_bounds__(NT2) void dfine_select_kernel(
    const float* __restrict__ logits,        // [B, N] (fallback only)
    const float* __restrict__ pboxes,        // [B, Q, 4]
    const float* __restrict__ sizes,         // [B, 2]
    const unsigned* __restrict__ cnt,        // [B]
    const unsigned long long* __restrict__ candG,  // [B*capG]
    float* __restrict__ out,
    int B, int Q, int C, int K, int capG)
{
    const int b   = blockIdx.x;
    const int tid = threadIdx.x;
    const int N   = Q * C;

    __shared__ unsigned long long cand[CAPL];
    __shared__ unsigned hist[NBINS];
    __shared__ unsigned partial[NT2];
    __shared__ unsigned candCount;
    __shared__ unsigned threshBin;

    const int lim = (capG < CAPL) ? capG : CAPL;
    const unsigned nG = cnt[b];
    int n;

    if (nG >= (unsigned)K && nG <= (unsigned)lim) {
        // ---- hot path: copy candidate list to LDS ----
        n = (int)nG;
        const unsigned long long* cb = candG + (long long)b * capG;
        for (int i = tid; i < n; i += NT2) cand[i] = cb[i];
        __syncthreads();
    } else {
        // ---- fallback: exact histogram selection over full batch ----
        const float* __restrict__ lg = logits + (long long)b * N;
        for (int i = tid; i < NBINS; i += NT2) hist[i] = 0u;
        if (tid == 0) candCount = 0u;
        __syncthreads();
        for (int i = tid; i < N; i += NT2)
            atomicAdd(&hist[f2key(lg[i]) >> 20], 1u);
        __syncthreads();
        {
            const int BPT = NBINS / NT2;
            unsigned s = 0;
            #pragma unroll
            for (int m = 0; m < BPT; ++m) s += hist[tid * BPT + m];
            partial[tid] = s;
        }
        __syncthreads();
        if (tid < 64) {
            const int PPG = NT2 / 64;
            unsigned gs = 0;
            #pragma unroll
            for (int m = 0; m < PPG; ++m) gs += partial[tid * PPG + m];
            unsigned pre = gs;
            #pragma unroll
            for (int off = 1; off < 64; off <<= 1) {
                unsigned t = __shfl_up(pre, off);
                if (tid >= off) pre += t;
            }
            unsigned total = __shfl(pre, 63);
            unsigned suf   = total - (pre - gs);
            unsigned long long m1 = __ballot(suf >= (unsigned)K);
            int g = 63 - __clzll(m1);
            unsigned above = total - __shfl(pre, g);
            unsigned hv = hist[g * 64 + tid];
            unsigned pre2 = hv;
            #pragma unroll
            for (int off = 1; off < 64; off <<= 1) {
                unsigned t = __shfl_up(pre2, off);
                if (tid >= off) pre2 += t;
            }
            unsigned total2 = __shfl(pre2, 63);
            unsigned suf2   = above + total2 - (pre2 - hv);
            unsigned long long m2 = __ballot(suf2 >= (unsigned)K);
            int l2 = 63 - __clzll(m2);
            if (tid == 0) threshBin = (unsigned)(g * 64 + l2);
        }
        __syncthreads();
        const unsigned tb = threshBin;
        for (int i = tid; i < N; i += NT2) {
            unsigned k = f2key(lg[i]);
            if ((k >> 20) >= tb) {
                unsigned p = atomicAdd(&candCount, 1u);
                if (p < (unsigned)CAPL) cand[p] = packkv(k, (unsigned)i);
            }
        }
        __syncthreads();
        n = (int)min(candCount, (unsigned)CAPL);
    }

    // ---- rank-based selection + emit ----
    const int BK = B * K;
    float* __restrict__ out_labels = out;
    float* __restrict__ out_boxes  = out + BK;
    float* __restrict__ out_scores = out + (long long)BK * 5;
    const float s0 = sizes[2 * b];
    const float s1 = sizes[2 * b + 1];

    for (int t = tid; t < n; t += NT2) {
        unsigned long long my = cand[t];
        int r = 0;
        for (int j = 0; j < n; ++j) r += (cand[j] > my);   // packed keys unique
        if (r < K) {
            unsigned key = (unsigned)(my >> 32);
            unsigned idx = 0xFFFFFFFFu - (unsigned)(my & 0xFFFFFFFFull);
            float logit = key2f(key);
            float score = 1.0f / (1.0f + expf(-logit));
            int label = (int)(idx % (unsigned)C);
            int q     = (int)(idx / (unsigned)C);
            float4 bp = *reinterpret_cast<const float4*>(pboxes + ((long long)b * Q + q) * 4);
            int o = b * K + r;
            out_labels[o] = (float)label;
            out_scores[o] = score;
            float4 bb;
            bb.x = (bp.x - 0.5f * bp.z) * s0;
            bb.y = (bp.y - 0.5f * bp.w) * s1;
            bb.z = (bp.x + 0.5f * bp.z) * s0;
            bb.w = (bp.y + 0.5f * bp.w) * s1;
            *reinterpret_cast<float4*>(out_boxes + 4LL * o) = bb;
        }
    }
}

extern "C" void kernel_launch(void* const* d_in, const int* in_sizes, int n_in,
                              void* d_out, int out_size, void* d_ws, size_t ws_size,
                              hipStream_t stream) {
    const float* logits = (const float*)d_in[0];
    const float* pboxes = (const float*)d_in[1];
    const float* sizes  = (const float*)d_in[2];

    const int B = in_sizes[2] / 2;                 // 256
    const int Q = in_sizes[1] / (4 * B);           // 1000
    const int C = in_sizes[0] / (B * Q);           // 80
    const int K = out_size / (6 * B);              // 300
    const int N = Q * C;
    const int N4 = N / 4;
    const int TOT4 = B * N4;

    // workspace layout: cnt[B] (zeroed each call) | candG[B*capG]
    unsigned* cnt = (unsigned*)d_ws;
    unsigned long long* candG =
        (unsigned long long*)((char*)d_ws + ((B * sizeof(unsigned) + 255) & ~255ull));
    size_t cand_off = ((B * sizeof(unsigned) + 255) & ~255ull);
    long long avail = (long long)ws_size - (long long)cand_off;
    int capG = (avail > 0) ? (int)(avail / ((long long)B * 8)) : 0;
    if (capG > CAPL) capG = CAPL;
    if (capG < 0) capG = 0;
    // capG < ~700 => select kernel falls back per batch (slow but correct)

    hipMemsetAsync(d_ws, 0, B * sizeof(unsigned), stream);
    dfine_filter_kernel<<<2048, 256, 0, stream>>>(
        (const float4*)logits, cnt, candG, TOT4, N4, capG);
    dfine_select_kernel<<<B, NT2, 0, stream>>>(
        logits, pboxes, sizes, cnt, candG, (float*)d_out, B, Q, C, K, capG);
}

// Round 6
// 42.409 us; speedup vs baseline: 14.1581x; 14.1581x over previous
//
#include <hip/hip_runtime.h>

// D-FINE post-processor, two-kernel decomposition, block-local compaction.
//   K1 (filter): 8 blocks per batch, each owns a contiguous 1/8 slice.
//       Streaming float4 reads (4 in flight via sched_barrier), hits
//       (logit > THR) compacted into an LDS list, then ONE global
//       atomicAdd per block reserves a window in the per-batch candidate
//       list; coalesced LDS->global copy. LDS overflow poisons cnt[b]
//       (atomicOr top bit) -> K2 falls back to exact histogram selection.
//   K2 (select): one block per batch; candidates -> LDS, rank-based
//       selection (count-of-greater on packed (key<<32)|~idx = exact
//       jax.lax.top_k tie semantics), decode boxes, emit.
// Output (float32): labels [B*K] | boxes [B*K*4] | scores [B*K]

constexpr int   NT1   = 256;    // filter block
constexpr int   BPB   = 8;      // filter blocks per batch
constexpr int   LCAP  = 2048;   // per-block LDS candidate cap (16 KB)
constexpr int   NT2   = 1024;   // select block
constexpr int   NBINS = 4096;
constexpr int   CAPL  = 4096;   // per-batch candidate cap in LDS (select)
constexpr float THR   = 2.4f;   // static pre-filter (fallback makes it safe)

__device__ __forceinline__ unsigned f2key(float f) {
    unsigned u = __float_as_uint(f);
    return (u & 0x80000000u) ? ~u : (u | 0x80000000u);
}
__device__ __forceinline__ float key2f(unsigned k) {
    unsigned u = (k & 0x80000000u) ? (k & 0x7FFFFFFFu) : ~k;
    return __uint_as_float(u);
}
__device__ __forceinline__ unsigned long long packkv(unsigned key, unsigned idx) {
    return ((unsigned long long)key << 32) | (unsigned long long)(0xFFFFFFFFu - idx);
}

// ---------------- Kernel 1: streaming filter, block-local compaction ----------------
__global__ __launch_bounds__(NT1) void dfine_filter_kernel(
    const float4* __restrict__ lg4,          // [B * N4]
    unsigned* __restrict__ cnt,              // [B] (zeroed)
    unsigned long long* __restrict__ candG,  // [B * capG]
    int N4, int capG)
{
    const int b     = blockIdx.x / BPB;
    const int slice = blockIdx.x % BPB;
    const int chunk = (N4 + BPB - 1) / BPB;          // 2500
    const int lo    = slice * chunk;
    const int hi    = (lo + chunk < N4) ? (lo + chunk) : N4;
    const float4* __restrict__ base4 = lg4 + (long long)b * N4;

    __shared__ unsigned long long lc[LCAP];
    __shared__ unsigned lcnt;
    __shared__ unsigned gbase;
    if (threadIdx.x == 0) lcnt = 0u;
    __syncthreads();

    for (int s = lo; s < hi; s += 4 * NT1) {
        float4 v[4];
        #pragma unroll
        for (int j = 0; j < 4; ++j) {
            int i4 = s + j * NT1 + threadIdx.x;
            int c  = (i4 < hi) ? i4 : (hi - 1);      // clamped load, predicated use
            v[j] = base4[c];
        }
        __builtin_amdgcn_sched_barrier(0);           // keep 4 loads in flight
        #pragma unroll
        for (int j = 0; j < 4; ++j) {
            int i4 = s + j * NT1 + threadIdx.x;
            if (i4 < hi) {
                if (v[j].x > THR || v[j].y > THR || v[j].z > THR || v[j].w > THR) {
                    unsigned bi = (unsigned)(4 * i4);
                    if (v[j].x > THR) { unsigned p = atomicAdd(&lcnt, 1u);
                        if (p < (unsigned)LCAP) lc[p] = packkv(f2key(v[j].x), bi + 0); }
                    if (v[j].y > THR) { unsigned p = atomicAdd(&lcnt, 1u);
                        if (p < (unsigned)LCAP) lc[p] = packkv(f2key(v[j].y), bi + 1); }
                    if (v[j].z > THR) { unsigned p = atomicAdd(&lcnt, 1u);
                        if (p < (unsigned)LCAP) lc[p] = packkv(f2key(v[j].z), bi + 2); }
                    if (v[j].w > THR) { unsigned p = atomicAdd(&lcnt, 1u);
                        if (p < (unsigned)LCAP) lc[p] = packkv(f2key(v[j].w), bi + 3); }
                }
            }
        }
    }
    __syncthreads();

    const unsigned m = lcnt;
    if (threadIdx.x == 0) {
        if (m <= (unsigned)LCAP) gbase = atomicAdd(&cnt[b], m);          // one atomic/block
        else { atomicOr(&cnt[b], 0x80000000u); gbase = 0xFFFFFFFFu; }    // poison -> fallback
    }
    __syncthreads();

    const unsigned gb = gbase;
    const unsigned mm = (m <= (unsigned)LCAP) ? m : 0u;
    unsigned long long* __restrict__ cb = candG + (long long)b * capG;
    for (unsigned i = threadIdx.x; i < mm; i += NT1) {
        unsigned p = gb + i;
        if (p < (unsigned)capG) cb[p] = lc[i];
    }
}

// ---------------- Kernel 2: per-batch select + emit ----------------
__global__ __launch_bounds__(NT2) void dfine_select_kernel(
    const float* __restrict__ logits,              // [B, N] (fallback only)
    const float* __restrict__ pboxes,              // [B, Q, 4]
    const float* __restrict__ sizes,               // [B, 2]
    const unsigned* __restrict__ cnt,              // [B]
    const unsigned long long* __restrict__ candG,  // [B * capG]
    float* __restrict__ out,
    int B, int Q, int C, int K, int capG)
{
    const int b   = blockIdx.x;
    const int tid = threadIdx.x;
    const int N   = Q * C;

    __shared__ unsigned long long cand[CAPL];
    __shared__ unsigned hist[NBINS];
    __shared__ unsigned partial[NT2];
    __shared__ unsigned candCount;
    __shared__ unsigned threshBin;

    const int lim = (capG < CAPL) ? capG : CAPL;
    const unsigned nG = cnt[b];
    int n;

    if (nG >= (unsigned)K && nG <= (unsigned)lim) {
        // ---- hot path: candidate list -> LDS ----
        n = (int)nG;
        const unsigned long long* cb = candG + (long long)b * capG;
        for (int i = tid; i < n; i += NT2) cand[i] = cb[i];
        __syncthreads();
    } else {
        // ---- fallback: exact histogram selection over the full batch ----
        const float* __restrict__ lg = logits + (long long)b * N;
        for (int i = tid; i < NBINS; i += NT2) hist[i] = 0u;
        if (tid == 0) candCount = 0u;
        __syncthreads();
        for (int i = tid; i < N; i += NT2)
            atomicAdd(&hist[f2key(lg[i]) >> 20], 1u);
        __syncthreads();
        {
            const int BPT = NBINS / NT2;
            unsigned s = 0;
            #pragma unroll
            for (int m = 0; m < BPT; ++m) s += hist[tid * BPT + m];
            partial[tid] = s;
        }
        __syncthreads();
        if (tid < 64) {
            const int PPG = NT2 / 64;
            unsigned gs = 0;
            #pragma unroll
            for (int m = 0; m < PPG; ++m) gs += partial[tid * PPG + m];
            unsigned pre = gs;
            #pragma unroll
            for (int off = 1; off < 64; off <<= 1) {
                unsigned t = __shfl_up(pre, off);
                if (tid >= off) pre += t;
            }
            unsigned total = __shfl(pre, 63);
            unsigned suf   = total - (pre - gs);
            unsigned long long m1 = __ballot(suf >= (unsigned)K);
            int g = 63 - __clzll(m1);
            unsigned above = total - __shfl(pre, g);
            unsigned hv = hist[g * 64 + tid];
            unsigned pre2 = hv;
            #pragma unroll
            for (int off = 1; off < 64; off <<= 1) {
                unsigned t = __shfl_up(pre2, off);
                if (tid >= off) pre2 += t;
            }
            unsigned total2 = __shfl(pre2, 63);
            unsigned suf2   = above + total2 - (pre2 - hv);
            unsigned long long m2 = __ballot(suf2 >= (unsigned)K);
            int l2 = 63 - __clzll(m2);
            if (tid == 0) threshBin = (unsigned)(g * 64 + l2);
        }
        __syncthreads();
        const unsigned tb = threshBin;
        for (int i = tid; i < N; i += NT2) {
            unsigned k = f2key(lg[i]);
            if ((k >> 20) >= tb) {
                unsigned p = atomicAdd(&candCount, 1u);
                if (p < (unsigned)CAPL) cand[p] = packkv(k, (unsigned)i);
            }
        }
        __syncthreads();
        n = (int)min(candCount, (unsigned)CAPL);
    }

    // ---- rank-based selection + emit ----
    const int BK = B * K;
    float* __restrict__ out_labels = out;
    float* __restrict__ out_boxes  = out + BK;
    float* __restrict__ out_scores = out + (long long)BK * 5;
    const float s0 = sizes[2 * b];
    const float s1 = sizes[2 * b + 1];

    for (int t = tid; t < n; t += NT2) {
        unsigned long long my = cand[t];
        int r = 0;
        for (int j = 0; j < n; ++j) r += (cand[j] > my);   // packed keys unique
        if (r < K) {
            unsigned key = (unsigned)(my >> 32);
            unsigned idx = 0xFFFFFFFFu - (unsigned)(my & 0xFFFFFFFFull);
            float logit = key2f(key);
            float score = 1.0f / (1.0f + expf(-logit));
            int label = (int)(idx % (unsigned)C);
            int q     = (int)(idx / (unsigned)C);
            float4 bp = *reinterpret_cast<const float4*>(pboxes + ((long long)b * Q + q) * 4);
            int o = b * K + r;
            out_labels[o] = (float)label;
            out_scores[o] = score;
            float4 bb;
            bb.x = (bp.x - 0.5f * bp.z) * s0;
            bb.y = (bp.y - 0.5f * bp.w) * s1;
            bb.z = (bp.x + 0.5f * bp.z) * s0;
            bb.w = (bp.y + 0.5f * bp.w) * s1;
            *reinterpret_cast<float4*>(out_boxes + 4LL * o) = bb;
        }
    }
}

extern "C" void kernel_launch(void* const* d_in, const int* in_sizes, int n_in,
                              void* d_out, int out_size, void* d_ws, size_t ws_size,
                              hipStream_t stream) {
    const float* logits = (const float*)d_in[0];
    const float* pboxes = (const float*)d_in[1];
    const float* sizes  = (const float*)d_in[2];

    const int B = in_sizes[2] / 2;                 // 256
    const int Q = in_sizes[1] / (4 * B);           // 1000
    const int C = in_sizes[0] / (B * Q);           // 80
    const int K = out_size / (6 * B);              // 300
    const int N = Q * C;
    const int N4 = N / 4;

    // workspace layout: cnt[B] (zeroed each call) | candG[B*capG]
    unsigned* cnt = (unsigned*)d_ws;
    size_t cand_off = ((B * sizeof(unsigned) + 255) & ~255ull);
    unsigned long long* candG = (unsigned long long*)((char*)d_ws + cand_off);
    long long avail = (long long)ws_size - (long long)cand_off;
    int capG = (avail > 0) ? (int)(avail / ((long long)B * 8)) : 0;
    if (capG > CAPL) capG = CAPL;
    if (capG < 0) capG = 0;
    // capG below typical candidate count => select kernel falls back (slow, correct)

    hipMemsetAsync(d_ws, 0, B * sizeof(unsigned), stream);
    dfine_filter_kernel<<<B * BPB, NT1, 0, stream>>>(
        (const float4*)logits, cnt, candG, N4, capG);
    dfine_select_kernel<<<B, NT2, 0, stream>>>(
        logits, pboxes, sizes, cnt, candG, (float*)d_out, B, Q, C, K, capG);
}

// Round 7
// 37.259 us; speedup vs baseline: 16.1150x; 1.1382x over previous
//
#include <hip/hip_runtime.h>

// D-FINE post-processor, two kernels, segmented candidate lists (no global
// atomics, no memset, fully deterministic):
//   K1 (filter): B*BPB blocks; block (b,slice) owns logits slice and a PRIVATE
//       segment candG[(b*BPB+slice)*SEG .. +SEG). Streaming float4 reads
//       (4 in flight via sched_barrier); hits (logit > THR) scatter into the
//       segment at an LDS-counter offset; true hit count written to
//       scnt[b*BPB+slice] unconditionally (overwrites stale state each call).
//   K2 (select): one block per batch; reads 8 segment counts, prefix-sums,
//       bound-checks (m_s <= SEG for all s, K <= total <= CAPL), loads segments
//       into LDS, rank-based selection (count-of-greater on packed
//       (key<<32)|~idx = exact jax.lax.top_k tie semantics), decodes + emits.
//       Exact histogram FALLBACK over the batch if the bound check fails.
// {x > THR} is a prefix of the descending score order, so when the bound check
// passes the candidate set provably contains the top-K.
// Output (float32): labels [B*K] | boxes [B*K*4] | scores [B*K]

constexpr int   NT1   = 256;    // filter block
constexpr int   BPB   = 8;      // filter blocks (segments) per batch
constexpr int   SEG   = 512;    // slots per segment (expected ~82 hits, ~47 sigma)
constexpr int   NT2   = 1024;   // select block
constexpr int   NBINS = 4096;
constexpr int   CAPL  = 4096;   // per-batch candidate cap in LDS (select)
constexpr float THR   = 2.4f;   // static pre-filter (fallback makes it safe)

__device__ __forceinline__ unsigned f2key(float f) {
    unsigned u = __float_as_uint(f);
    return (u & 0x80000000u) ? ~u : (u | 0x80000000u);
}
__device__ __forceinline__ float key2f(unsigned k) {
    unsigned u = (k & 0x80000000u) ? (k & 0x7FFFFFFFu) : ~k;
    return __uint_as_float(u);
}
__device__ __forceinline__ unsigned long long packkv(unsigned key, unsigned idx) {
    return ((unsigned long long)key << 32) | (unsigned long long)(0xFFFFFFFFu - idx);
}

// ---------------- Kernel 1: streaming filter into private segments ----------------
__global__ __launch_bounds__(NT1) void dfine_filter_kernel(
    const float4* __restrict__ lg4,          // [B * N4]
    unsigned* __restrict__ scnt,             // [B * BPB]  (overwritten each call)
    unsigned long long* __restrict__ candG,  // [B * BPB * seg]
    int N4, int seg)
{
    const int blk   = blockIdx.x;
    const int b     = blk / BPB;
    const int slice = blk % BPB;
    const int chunk = (N4 + BPB - 1) / BPB;          // 2500
    const int lo    = slice * chunk;
    const int hi    = (lo + chunk < N4) ? (lo + chunk) : N4;
    const float4* __restrict__ base4 = lg4 + (long long)b * N4;
    unsigned long long* __restrict__ segp = candG + (long long)blk * seg;

    __shared__ unsigned lcnt;
    if (threadIdx.x == 0) lcnt = 0u;
    __syncthreads();

    for (int s = lo; s < hi; s += 4 * NT1) {
        float4 v[4];
        #pragma unroll
        for (int j = 0; j < 4; ++j) {
            int i4 = s + j * NT1 + threadIdx.x;
            int c  = (i4 < hi) ? i4 : (hi - 1);      // clamped load, predicated use
            v[j] = base4[c];
        }
        __builtin_amdgcn_sched_barrier(0);           // keep 4 loads in flight
        #pragma unroll
        for (int j = 0; j < 4; ++j) {
            int i4 = s + j * NT1 + threadIdx.x;
            if (i4 < hi) {
                if (v[j].x > THR || v[j].y > THR || v[j].z > THR || v[j].w > THR) {
                    unsigned bi = (unsigned)(4 * i4);
                    if (v[j].x > THR) { unsigned p = atomicAdd(&lcnt, 1u);
                        if (p < (unsigned)seg) segp[p] = packkv(f2key(v[j].x), bi + 0); }
                    if (v[j].y > THR) { unsigned p = atomicAdd(&lcnt, 1u);
                        if (p < (unsigned)seg) segp[p] = packkv(f2key(v[j].y), bi + 1); }
                    if (v[j].z > THR) { unsigned p = atomicAdd(&lcnt, 1u);
                        if (p < (unsigned)seg) segp[p] = packkv(f2key(v[j].z), bi + 2); }
                    if (v[j].w > THR) { unsigned p = atomicAdd(&lcnt, 1u);
                        if (p < (unsigned)seg) segp[p] = packkv(f2key(v[j].w), bi + 3); }
                }
            }
        }
    }
    __syncthreads();
    if (threadIdx.x == 0) scnt[blk] = lcnt;          // true count (may exceed seg -> fallback)
}

// ---------------- Kernel 2: per-batch select + emit ----------------
__global__ __launch_bounds__(NT2) void dfine_select_kernel(
    const float* __restrict__ logits,              // [B, N] (fallback only)
    const float* __restrict__ pboxes,              // [B, Q, 4]
    const float* __restrict__ sizes,               // [B, 2]
    const unsigned* __restrict__ scnt,             // [B * BPB]
    const unsigned long long* __restrict__ candG,  // [B * BPB * seg]
    float* __restrict__ out,
    int B, int Q, int C, int K, int seg)
{
    const int b   = blockIdx.x;
    const int tid = threadIdx.x;
    const int N   = Q * C;

    __shared__ unsigned long long cand[CAPL];
    __shared__ unsigned hist[NBINS];
    __shared__ unsigned partial[NT2];
    __shared__ unsigned msz[BPB], moff[BPB];
    __shared__ unsigned candCount;
    __shared__ unsigned threshBin;
    __shared__ int hot;

    if (tid < BPB) msz[tid] = scnt[b * BPB + tid];
    __syncthreads();
    if (tid == 0) {
        unsigned tot = 0; int ok = 1;
        #pragma unroll
        for (int s = 0; s < BPB; ++s) {
            moff[s] = tot;
            if (msz[s] > (unsigned)seg) ok = 0;
            tot += msz[s];
        }
        candCount = tot;
        hot = ok && tot >= (unsigned)K && tot <= (unsigned)CAPL;
    }
    __syncthreads();

    int n;
    if (hot) {
        // ---- hot path: copy 8 segments compactly into LDS ----
        n = (int)candCount;
        #pragma unroll
        for (int s = 0; s < BPB; ++s) {
            const unsigned long long* sp = candG + (long long)(b * BPB + s) * seg;
            unsigned m = msz[s], o = moff[s];
            for (unsigned i = tid; i < m; i += NT2) cand[o + i] = sp[i];
        }
        __syncthreads();
    } else {
        // ---- fallback: exact histogram selection over the full batch ----
        const float* __restrict__ lg = logits + (long long)b * N;
        for (int i = tid; i < NBINS; i += NT2) hist[i] = 0u;
        if (tid == 0) candCount = 0u;
        __syncthreads();
        for (int i = tid; i < N; i += NT2)
            atomicAdd(&hist[f2key(lg[i]) >> 20], 1u);
        __syncthreads();
        {
            const int BPT = NBINS / NT2;
            unsigned s = 0;
            #pragma unroll
            for (int m = 0; m < BPT; ++m) s += hist[tid * BPT + m];
            partial[tid] = s;
        }
        __syncthreads();
        if (tid < 64) {
            const int PPG = NT2 / 64;
            unsigned gs = 0;
            #pragma unroll
            for (int m = 0; m < PPG; ++m) gs += partial[tid * PPG + m];
            unsigned pre = gs;
            #pragma unroll
            for (int off = 1; off < 64; off <<= 1) {
                unsigned t = __shfl_up(pre, off);
                if (tid >= off) pre += t;
            }
            unsigned total = __shfl(pre, 63);
            unsigned suf   = total - (pre - gs);
            unsigned long long m1 = __ballot(suf >= (unsigned)K);
            int g = 63 - __clzll(m1);
            unsigned above = total - __shfl(pre, g);
            unsigned hv = hist[g * 64 + tid];
            unsigned pre2 = hv;
            #pragma unroll
            for (int off = 1; off < 64; off <<= 1) {
                unsigned t = __shfl_up(pre2, off);
                if (tid >= off) pre2 += t;
            }
            unsigned total2 = __shfl(pre2, 63);
            unsigned suf2   = above + total2 - (pre2 - hv);
            unsigned long long m2 = __ballot(suf2 >= (unsigned)K);
            int l2 = 63 - __clzll(m2);
            if (tid == 0) threshBin = (unsigned)(g * 64 + l2);
        }
        __syncthreads();
        const unsigned tb = threshBin;
        if (tid == 0) candCount = 0u;
        __syncthreads();
        for (int i = tid; i < N; i += NT2) {
            unsigned k = f2key(lg[i]);
            if ((k >> 20) >= tb) {
                unsigned p = atomicAdd(&candCount, 1u);
                if (p < (unsigned)CAPL) cand[p] = packkv(k, (unsigned)i);
            }
        }
        __syncthreads();
        n = (int)min(candCount, (unsigned)CAPL);
    }

    // ---- rank-based selection + emit ----
    const int BK = B * K;
    float* __restrict__ out_labels = out;
    float* __restrict__ out_boxes  = out + BK;
    float* __restrict__ out_scores = out + (long long)BK * 5;
    const float s0 = sizes[2 * b];
    const float s1 = sizes[2 * b + 1];

    for (int t = tid; t < n; t += NT2) {
        unsigned long long my = cand[t];
        int r = 0;
        for (int j = 0; j < n; ++j) r += (cand[j] > my);   // packed keys unique
        if (r < K) {
            unsigned key = (unsigned)(my >> 32);
            unsigned idx = 0xFFFFFFFFu - (unsigned)(my & 0xFFFFFFFFull);
            float logit = key2f(key);
            float score = 1.0f / (1.0f + expf(-logit));
            int label = (int)(idx % (unsigned)C);
            int q     = (int)(idx / (unsigned)C);
            float4 bp = *reinterpret_cast<const float4*>(pboxes + ((long long)b * Q + q) * 4);
            int o = b * K + r;
            out_labels[o] = (float)label;
            out_scores[o] = score;
            float4 bb;
            bb.x = (bp.x - 0.5f * bp.z) * s0;
            bb.y = (bp.y - 0.5f * bp.w) * s1;
            bb.z = (bp.x + 0.5f * bp.z) * s0;
            bb.w = (bp.y + 0.5f * bp.w) * s1;
            *reinterpret_cast<float4*>(out_boxes + 4LL * o) = bb;
        }
    }
}

extern "C" void kernel_launch(void* const* d_in, const int* in_sizes, int n_in,
                              void* d_out, int out_size, void* d_ws, size_t ws_size,
                              hipStream_t stream) {
    const float* logits = (const float*)d_in[0];
    const float* pboxes = (const float*)d_in[1];
    const float* sizes  = (const float*)d_in[2];

    const int B = in_sizes[2] / 2;                 // 256
    const int Q = in_sizes[1] / (4 * B);           // 1000
    const int C = in_sizes[0] / (B * Q);           // 80
    const int K = out_size / (6 * B);              // 300
    const int N = Q * C;
    const int N4 = N / 4;
    const int NSEGS = B * BPB;

    // workspace layout: scnt[B*BPB] | candG[B*BPB*seg]   (no zeroing required)
    unsigned* scnt = (unsigned*)d_ws;
    size_t cand_off = (((size_t)NSEGS * sizeof(unsigned) + 255) & ~(size_t)255);
    unsigned long long* candG = (unsigned long long*)((char*)d_ws + cand_off);
    long long avail = (long long)ws_size - (long long)cand_off;
    int seg = (avail > 0) ? (int)(avail / ((long long)NSEGS * 8)) : 0;
    if (seg > SEG) seg = SEG;
    if (seg < 0) seg = 0;
    // seg too small => per-slice counts exceed seg => select falls back (correct)

    dfine_filter_kernel<<<NSEGS, NT1, 0, stream>>>(
        (const float4*)logits, scnt, candG, N4, seg);
    dfine_select_kernel<<<B, NT2, 0, stream>>>(
        logits, pboxes, sizes, scnt, candG, (float*)d_out, B, Q, C, K, seg);
}